// Round 1
// baseline (277.446 us; speedup 1.0000x reference)
//
#include <hip/hip_runtime.h>
#include <hip/hip_bf16.h>
#include <stdint.h>

#define B_DIM 32
#define T_DIM 1024
#define C_DIM 768

typedef __bf16 bf16x8 __attribute__((ext_vector_type(8)));
typedef float f32x4 __attribute__((ext_vector_type(4)));

typedef __attribute__((address_space(1))) void gvoid_t;
typedef __attribute__((address_space(3))) void lvoid_t;

__device__ __forceinline__ unsigned short f32_to_bf16_rne(float f) {
    union { float f; uint32_t u; } v; v.f = f;
    uint32_t u = v.u;
    uint32_t r = 0x7fffu + ((u >> 16) & 1u);
    return (unsigned short)((u + r) >> 16);
}

// One wave per row: compute 1/||x||_2 and store normalized row as bf16.
__global__ __launch_bounds__(256) void normalize_rows(const float* __restrict__ x,
                                                      unsigned short* __restrict__ m) {
    const int row  = blockIdx.x * 4 + (threadIdx.x >> 6);
    const int lane = threadIdx.x & 63;
    const float4* xr = (const float4*)(x + (size_t)row * C_DIM);
    float4 v0 = xr[lane];
    float4 v1 = xr[lane + 64];
    float4 v2 = xr[lane + 128];
    float ss = v0.x*v0.x + v0.y*v0.y + v0.z*v0.z + v0.w*v0.w
             + v1.x*v1.x + v1.y*v1.y + v1.z*v1.z + v1.w*v1.w
             + v2.x*v2.x + v2.y*v2.y + v2.z*v2.z + v2.w*v2.w;
    #pragma unroll
    for (int off = 32; off > 0; off >>= 1)
        ss += __shfl_xor(ss, off, 64);
    const float rs = rsqrtf(ss);
    ushort4* mr = (ushort4*)(m + (size_t)row * C_DIM);
    ushort4 o;
    o.x = f32_to_bf16_rne(v0.x * rs); o.y = f32_to_bf16_rne(v0.y * rs);
    o.z = f32_to_bf16_rne(v0.z * rs); o.w = f32_to_bf16_rne(v0.w * rs);
    mr[lane] = o;
    o.x = f32_to_bf16_rne(v1.x * rs); o.y = f32_to_bf16_rne(v1.y * rs);
    o.z = f32_to_bf16_rne(v1.z * rs); o.w = f32_to_bf16_rne(v1.w * rs);
    mr[lane + 64] = o;
    o.x = f32_to_bf16_rne(v2.x * rs); o.y = f32_to_bf16_rne(v2.y * rs);
    o.z = f32_to_bf16_rne(v2.z * rs); o.w = f32_to_bf16_rne(v2.w * rs);
    mr[lane + 128] = o;
}

// Batched NT GEMM: out[b,i,j] = 1 - sum_k M[b,i,k]*M[b,j,k]
// 128x128 tile / block, BK=32, 4 waves, each wave 4x4 of 16x16x32 bf16 MFMA.
__global__ __launch_bounds__(256) void gemm_nt(const unsigned short* __restrict__ M,
                                               float* __restrict__ out) {
    __shared__ unsigned short As[128 * 32];
    __shared__ unsigned short Bs[128 * 32];

    const int b  = blockIdx.z;
    const int ti = blockIdx.y;
    const int tj = blockIdx.x;

    const int tid  = threadIdx.x;
    const int wave = tid >> 6;
    const int lane = tid & 63;
    const int quad = lane >> 4;
    const int l16  = lane & 15;
    const int wi = wave >> 1;   // wave row within 2x2
    const int wj = wave & 1;    // wave col within 2x2

    const unsigned short* Mb = M + (size_t)b * T_DIM * C_DIM;

    // Staging layout: tile flattened row-major [128][32] bf16 = 8192 B.
    // Wave w handles chunks (2w) and (2w+1), each chunk = 64 lanes x 16 B = 1024 B.
    // Lane's element: flat bf16 idx = chunk*512 + lane*8 -> row = chunk*16 + (lane>>2),
    // col = (lane&3)*8. LDS dest = wave-uniform chunk base + lane*16 (HW rule).
    const int srow0 = (wave * 2 + 0) * 16 + (lane >> 2);
    const int srow1 = (wave * 2 + 1) * 16 + (lane >> 2);
    const int scol  = (lane & 3) * 8;

    const unsigned short* gA0 = Mb + (size_t)(ti * 128 + srow0) * C_DIM + scol;
    const unsigned short* gA1 = Mb + (size_t)(ti * 128 + srow1) * C_DIM + scol;
    const unsigned short* gB0 = Mb + (size_t)(tj * 128 + srow0) * C_DIM + scol;
    const unsigned short* gB1 = Mb + (size_t)(tj * 128 + srow1) * C_DIM + scol;

    unsigned short* lA0 = &As[(wave * 2 + 0) * 512];
    unsigned short* lA1 = &As[(wave * 2 + 1) * 512];
    unsigned short* lB0 = &Bs[(wave * 2 + 0) * 512];
    unsigned short* lB1 = &Bs[(wave * 2 + 1) * 512];

    f32x4 acc[4][4];
    #pragma unroll
    for (int i = 0; i < 4; ++i)
        #pragma unroll
        for (int j = 0; j < 4; ++j)
            acc[i][j] = (f32x4){0.f, 0.f, 0.f, 0.f};

    for (int k0 = 0; k0 < C_DIM; k0 += 32) {
        __builtin_amdgcn_global_load_lds((gvoid_t*)(gA0 + k0), (lvoid_t*)lA0, 16, 0, 0);
        __builtin_amdgcn_global_load_lds((gvoid_t*)(gA1 + k0), (lvoid_t*)lA1, 16, 0, 0);
        __builtin_amdgcn_global_load_lds((gvoid_t*)(gB0 + k0), (lvoid_t*)lB0, 16, 0, 0);
        __builtin_amdgcn_global_load_lds((gvoid_t*)(gB1 + k0), (lvoid_t*)lB1, 16, 0, 0);
        __syncthreads();

        bf16x8 af[4], bfr[4];
        #pragma unroll
        for (int ii = 0; ii < 4; ++ii) {
            af[ii]  = *(const bf16x8*)&As[(wi * 64 + ii * 16 + l16) * 32 + quad * 8];
            bfr[ii] = *(const bf16x8*)&Bs[(wj * 64 + ii * 16 + l16) * 32 + quad * 8];
        }
        #pragma unroll
        for (int ii = 0; ii < 4; ++ii)
            #pragma unroll
            for (int jj = 0; jj < 4; ++jj)
                acc[ii][jj] = __builtin_amdgcn_mfma_f32_16x16x32_bf16(af[ii], bfr[jj], acc[ii][jj], 0, 0, 0);
        __syncthreads();
    }

    // Epilogue: C/D layout col = lane&15, row = quad*4 + reg. out = 1 - acc.
    float* outb = out + (size_t)b * T_DIM * T_DIM;
    #pragma unroll
    for (int ii = 0; ii < 4; ++ii) {
        const int rowbase = ti * 128 + wi * 64 + ii * 16 + quad * 4;
        #pragma unroll
        for (int jj = 0; jj < 4; ++jj) {
            const int col = tj * 128 + wj * 64 + jj * 16 + l16;
            #pragma unroll
            for (int r = 0; r < 4; ++r)
                outb[(size_t)(rowbase + r) * T_DIM + col] = 1.0f - acc[ii][jj][r];
        }
    }
}

extern "C" void kernel_launch(void* const* d_in, const int* in_sizes, int n_in,
                              void* d_out, int out_size, void* d_ws, size_t ws_size,
                              hipStream_t stream) {
    const float* x = (const float*)d_in[0];
    float* out = (float*)d_out;
    unsigned short* metric = (unsigned short*)d_ws;  // 32768 x 768 bf16 = 48 MiB

    // Normalize: B*T = 32768 rows, 4 rows per 256-thread block.
    normalize_rows<<<dim3((B_DIM * T_DIM) / 4), dim3(256), 0, stream>>>(x, metric);
    // GEMM: grid (tj, ti, b) = (8, 8, 32) = 2048 blocks.
    gemm_nt<<<dim3(T_DIM / 128, T_DIM / 128, B_DIM), dim3(256), 0, stream>>>(metric, out);
}